// Round 10
// baseline (274.749 us; speedup 1.0000x reference)
//
#include <hip/hip_runtime.h>
#include <hip/hip_bf16.h>

// BLAST factorized linear. INSTRUMENTATION ROUND:
//   k1_T repeated 4x, k2_fused repeated 2x internally (both idempotent) so both
//   exceed the ~76us harness-fill threshold and surface in rocprof top-5 with
//   full per-kernel counters. prep rewritten with coalesced writes.

typedef __bf16 bf16x8 __attribute__((ext_vector_type(8)));
typedef __bf16 bf16x4 __attribute__((ext_vector_type(4)));
typedef float  f32x4  __attribute__((ext_vector_type(4)));

#define IN_DIM  4096
#define OUT_DIM 4096
#define NROWS   8192
#define BJ      16
#define BO      16
#define RANK    128
#define ROWE    136   // u_lds row stride (elems)

#define REP_K1  4
#define REP_K2  2

__device__ __forceinline__ bf16x4 cvt4(f32x4 v) {
  bf16x4 r;
  r[0] = (__bf16)v[0]; r[1] = (__bf16)v[1]; r[2] = (__bf16)v[2]; r[3] = (__bf16)v[3];
  return r;
}
__device__ __forceinline__ f32x4 lo4(bf16x8 v) {
  return (f32x4){(float)v[0], (float)v[1], (float)v[2], (float)v[3]};
}
__device__ __forceinline__ f32x4 hi4(bf16x8 v) {
  return (f32x4){(float)v[4], (float)v[5], (float)v[6], (float)v[7]};
}

// ---- prep: frag-order weights, coalesced OUTPUT writes ----
// vtf[(((j*8+rf)*8+ks)*64+lane)*8+e] = Vt[j][s=ks*32+(lane>>4)*8+e][r=rf*16+(lane&15)]
// utf[(((o*16+pf)*4+ks)*64+lane)*8+e] = U[o][r=ks*32+(lane>>4)*8+e][p=pf*16+(lane&15)]
__global__ __launch_bounds__(256) void prep_frag(
    const float* __restrict__ Vt, const float* __restrict__ U,
    __bf16* __restrict__ vtf, __bf16* __restrict__ utf)
{
  const int NV = BJ * 256 * RANK;   // 524288
  int v = blockIdx.x * 256 + threadIdx.x;
  if (v < NV) {
    const int e = v & 7, lane = (v >> 3) & 63, ks = (v >> 9) & 7,
              rf = (v >> 12) & 7, j = v >> 15;
    const int l = lane & 15, lh = lane >> 4;
    const int s = ks * 32 + lh * 8 + e, r = rf * 16 + l;
    vtf[v] = (__bf16)Vt[((size_t)(j * 256 + s)) * RANK + r];
  } else {
    const int u = v - NV;
    const int e = u & 7, lane = (u >> 3) & 63, ks = (u >> 9) & 3,
              pf = (u >> 11) & 15, o = u >> 15;
    const int l = lane & 15, lh = lane >> 4;
    const int r = ks * 32 + lh * 8 + e, p = pf * 16 + l;
    utf[u] = (__bf16)U[((size_t)(o * RANK + r)) * 256 + p];
  }
}

// ---- K1: T-tile GEMM. wg=256 (4 waves), tile 64 rows x 128 r, one j. REP_K1 reps. ----
__global__ __launch_bounds__(256, 4) void k1_T(
    const float* __restrict__ x, const __bf16* __restrict__ vtf,
    __bf16* __restrict__ T)
{
  __shared__ __bf16 X_lds[64 * 256];   // 32 KB

  const int tid  = threadIdx.x;
  const int lane = tid & 63;
  const int w    = tid >> 6;
  const int l15  = lane & 15;
  const int lhi  = lane >> 4;
  const int mt   = blockIdx.x >> 4;
  const int j    = blockIdx.x & 15;
  const size_t rowbase = (size_t)mt * 64;

  #pragma clang loop unroll(disable)
  for (int rep = 0; rep < REP_K1; ++rep) {
    asm volatile("" ::: "memory");
    if (rep) __syncthreads();     // protect X_lds restage

    #pragma unroll
    for (int i = 0; i < 16; ++i) {
      const int row = w * 16 + i;
      const f32x4 v = *(const f32x4*)(x + (rowbase + row) * IN_DIM + j * 256 + lane * 4);
      const int c = (lane >> 1) ^ (row & 15);
      *(bf16x4*)&X_lds[row * 256 + c * 8 + (lane & 1) * 4] = cvt4(v);
    }
    __syncthreads();

    f32x4 acc[2][4];
    #pragma unroll
    for (int a = 0; a < 2; ++a)
      #pragma unroll
      for (int b = 0; b < 4; ++b) acc[a][b] = (f32x4){0.f, 0.f, 0.f, 0.f};

    const __bf16* va = vtf + ((size_t)(j * 8 + w * 2) * 8) * 512 + lane * 8;
    #pragma unroll
    for (int ks = 0; ks < 8; ++ks) {
      bf16x8 bfr[4];
      #pragma unroll
      for (int nf = 0; nf < 4; ++nf) {
        const int c = (ks * 4 + lhi) ^ l15;
        bfr[nf] = *(const bf16x8*)&X_lds[(nf * 16 + l15) * 256 + c * 8];
      }
      const bf16x8 a0 = *(const bf16x8*)(va + (size_t)ks * 512);
      const bf16x8 a1 = *(const bf16x8*)(va + (size_t)(8 + ks) * 512);
      #pragma unroll
      for (int nf = 0; nf < 4; ++nf) {
        acc[0][nf] = __builtin_amdgcn_mfma_f32_16x16x32_bf16(a0, bfr[nf], acc[0][nf], 0, 0, 0);
        acc[1][nf] = __builtin_amdgcn_mfma_f32_16x16x32_bf16(a1, bfr[nf], acc[1][nf], 0, 0, 0);
      }
    }
    #pragma unroll
    for (int rfi = 0; rfi < 2; ++rfi)
      #pragma unroll
      for (int nf = 0; nf < 4; ++nf) {
        *(bf16x4*)&T[(rowbase + nf * 16 + l15) * 2048 + j * RANK + (w * 2 + rfi) * 16 + lhi * 4]
            = cvt4(acc[rfi][nf]);
      }
  }
}

// ---- K2f: fused fold + out-GEMM. wg=256 (4 waves), 64 rows x one o. REP_K2 reps. ----
// grid b: o = (b>>3)&15, mt = (b&7)*16 + (b>>7)  -> all 16 o's of an mt on one XCD.
__global__ __launch_bounds__(256, 4) void k2_fused(
    const __bf16* __restrict__ T, const float* __restrict__ S,
    const __bf16* __restrict__ utf, const float* __restrict__ bias,
    float* __restrict__ out)
{
  __shared__ float  S_lds[2048];        // 8 KB
  __shared__ __bf16 u_lds[64 * ROWE];   // 17 KB

  const int tid = threadIdx.x;
  const int b   = blockIdx.x;
  const int o   = (b >> 3) & 15;
  const int mt  = (b & 7) * 16 + (b >> 7);
  const size_t rowbase = (size_t)mt * 64;

  #pragma clang loop unroll(disable)
  for (int rep = 0; rep < REP_K2; ++rep) {
    asm volatile("" ::: "memory");
    if (rep) __syncthreads();     // protect S_lds/u_lds restage

    // stage S[o] permuted
    {
      const float* sb = S + (size_t)o * (BJ * RANK);
      #pragma unroll
      for (int h = 0; h < 2; ++h) {
        const int c  = tid + h * 256;
        const int jj = c >> 5, rr4 = c & 31;
        const f32x4 v = *(const f32x4*)(sb + (size_t)jj * RANK + rr4 * 4);
        *(f32x4*)&S_lds[(jj * 32 + (rr4 & 7) * 4 + (rr4 >> 3)) * 4] = v;
      }
    }
    __syncthreads();

    // fold in registers: thread = (n = tid>>2, rq = tid&3)
    {
      const int n  = tid >> 2;
      const int rq = tid & 3;
      const __bf16* tg = T + (rowbase + n) * 2048 + rq * 32;
      f32x4 uac[8];
      #pragma unroll
      for (int e = 0; e < 8; ++e) uac[e] = (f32x4){0.f, 0.f, 0.f, 0.f};

      #pragma unroll 4
      for (int jb = 0; jb < BJ; ++jb) {
        const bf16x8 tv0 = *(const bf16x8*)(tg + jb * RANK);
        const bf16x8 tv1 = *(const bf16x8*)(tg + jb * RANK + 8);
        const bf16x8 tv2 = *(const bf16x8*)(tg + jb * RANK + 16);
        const bf16x8 tv3 = *(const bf16x8*)(tg + jb * RANK + 24);
        const float* sj = &S_lds[(jb * 32 + rq) * 4];
        uac[0] = *(const f32x4*)(sj + 0 * 16) * lo4(tv0) + uac[0];
        uac[1] = *(const f32x4*)(sj + 1 * 16) * hi4(tv0) + uac[1];
        uac[2] = *(const f32x4*)(sj + 2 * 16) * lo4(tv1) + uac[2];
        uac[3] = *(const f32x4*)(sj + 3 * 16) * hi4(tv1) + uac[3];
        uac[4] = *(const f32x4*)(sj + 4 * 16) * lo4(tv2) + uac[4];
        uac[5] = *(const f32x4*)(sj + 5 * 16) * hi4(tv2) + uac[5];
        uac[6] = *(const f32x4*)(sj + 6 * 16) * lo4(tv3) + uac[6];
        uac[7] = *(const f32x4*)(sj + 7 * 16) * hi4(tv3) + uac[7];
      }
      #pragma unroll
      for (int e8 = 0; e8 < 4; ++e8) {
        bf16x8 uw;
        const f32x4 a = uac[2 * e8], bb = uac[2 * e8 + 1];
        uw[0] = (__bf16)a[0];  uw[1] = (__bf16)a[1];  uw[2] = (__bf16)a[2];  uw[3] = (__bf16)a[3];
        uw[4] = (__bf16)bb[0]; uw[5] = (__bf16)bb[1]; uw[6] = (__bf16)bb[2]; uw[7] = (__bf16)bb[3];
        *(bf16x8*)&u_lds[n * ROWE + rq * 32 + e8 * 8] = uw;
      }
    }
    __syncthreads();

    // out GEMM: wave w -> p = [w*64, +64); D=[p,n] -> f32x4 stores
    {
      const int lane = tid & 63;
      const int w    = tid >> 6;
      const int l15  = lane & 15;
      const int lhi  = lane >> 4;

      f32x4 acc[4][4];
      #pragma unroll
      for (int a = 0; a < 4; ++a)
        #pragma unroll
        for (int c = 0; c < 4; ++c) acc[a][c] = (f32x4){0.f, 0.f, 0.f, 0.f};

      #pragma unroll
      for (int ks = 0; ks < 4; ++ks) {
        bf16x8 ubf[4];
        #pragma unroll
        for (int nf = 0; nf < 4; ++nf)
          ubf[nf] = *(const bf16x8*)&u_lds[(nf * 16 + l15) * ROWE + ks * 32 + lhi * 8];
        #pragma unroll
        for (int pi = 0; pi < 4; ++pi) {
          const bf16x8 af = *(const bf16x8*)(
              utf + ((size_t)((o * 16 + w * 4 + pi) * 4 + ks)) * 512 + lane * 8);
          #pragma unroll
          for (int nf = 0; nf < 4; ++nf)
            acc[pi][nf] = __builtin_amdgcn_mfma_f32_16x16x32_bf16(af, ubf[nf], acc[pi][nf], 0, 0, 0);
        }
      }

      #pragma unroll
      for (int pi = 0; pi < 4; ++pi) {
        const int colb = o * 256 + (w * 4 + pi) * 16 + lhi * 4;
        const f32x4 bv = *(const f32x4*)(bias + colb);
        #pragma unroll
        for (int nf = 0; nf < 4; ++nf) {
          *(f32x4*)(out + (rowbase + nf * 16 + l15) * OUT_DIM + colb) = acc[pi][nf] + bv;
        }
      }
    }
  }
}

extern "C" void kernel_launch(void* const* d_in, const int* in_sizes, int n_in,
                              void* d_out, int out_size, void* d_ws, size_t ws_size,
                              hipStream_t stream) {
  const float* x    = (const float*)d_in[0];
  const float* S    = (const float*)d_in[1];
  const float* U    = (const float*)d_in[2];
  const float* Vt   = (const float*)d_in[3];
  const float* bias = (const float*)d_in[4];
  float* out = (float*)d_out;

  __bf16* vtf = (__bf16*)d_ws;                       // 1 MB
  __bf16* utf = vtf + (size_t)BJ * 8 * 8 * 512;      // 1 MB
  __bf16* T   = utf + (size_t)BO * 16 * 4 * 512;     // 32 MB: T[8192][2048]

  prep_frag<<<(2 * 524288) / 256, 256, 0, stream>>>(Vt, U, vtf, utf);
  k1_T<<<(NROWS / 64) * BJ, 256, 0, stream>>>(x, vtf, T);
  k2_fused<<<(NROWS / 64) * BO, 256, 0, stream>>>(T, S, utf, bias, out);
}

// Round 11
// 99.413 us; speedup vs baseline: 2.7637x; 2.7637x over previous
//
#include <hip/hip_runtime.h>
#include <hip/hip_bf16.h>

// BLAST factorized linear, 3 kernels:
//   prep: frag-order weights vtf/utf (coalesced writes)
//   K1  : T[j][n][r] = sum_s X[n,j*256+s]*Vt[j,s,r]     (GEMM, X via LDS; j-major T)
//   K2f : per (64-row tile, o):
//         S[o] -> LDS linear; fold u[n,r] = sum_j S*T in regs
//           (T loads: 16x64B full sectors/instr via re-striped per-thread pieces)
//         u -> XOR-swizzled LDS; out = bias + u @ U_o (MFMA, frag-order utf)

typedef __bf16 bf16x8 __attribute__((ext_vector_type(8)));
typedef __bf16 bf16x4 __attribute__((ext_vector_type(4)));
typedef float  f32x4  __attribute__((ext_vector_type(4)));

#define IN_DIM  4096
#define OUT_DIM 4096
#define NROWS   8192
#define BJ      16
#define BO      16
#define RANK    128

__device__ __forceinline__ bf16x4 cvt4(f32x4 v) {
  bf16x4 r;
  r[0] = (__bf16)v[0]; r[1] = (__bf16)v[1]; r[2] = (__bf16)v[2]; r[3] = (__bf16)v[3];
  return r;
}
__device__ __forceinline__ f32x4 lo4(bf16x8 v) {
  return (f32x4){(float)v[0], (float)v[1], (float)v[2], (float)v[3]};
}
__device__ __forceinline__ f32x4 hi4(bf16x8 v) {
  return (f32x4){(float)v[4], (float)v[5], (float)v[6], (float)v[7]};
}

// ---- prep: frag-order weights, coalesced OUTPUT writes ----
// vtf[(((j*8+rf)*8+ks)*64+lane)*8+e] = Vt[j][s=ks*32+(lane>>4)*8+e][r=rf*16+(lane&15)]
// utf[(((o*16+pf)*4+ks)*64+lane)*8+e] = U[o][r=ks*32+(lane>>4)*8+e][p=pf*16+(lane&15)]
__global__ __launch_bounds__(256) void prep_frag(
    const float* __restrict__ Vt, const float* __restrict__ U,
    __bf16* __restrict__ vtf, __bf16* __restrict__ utf)
{
  const int NV = BJ * 256 * RANK;   // 524288
  int v = blockIdx.x * 256 + threadIdx.x;
  if (v < NV) {
    const int e = v & 7, lane = (v >> 3) & 63, ks = (v >> 9) & 7,
              rf = (v >> 12) & 7, j = v >> 15;
    const int l = lane & 15, lh = lane >> 4;
    const int s = ks * 32 + lh * 8 + e, r = rf * 16 + l;
    vtf[v] = (__bf16)Vt[((size_t)(j * 256 + s)) * RANK + r];
  } else {
    const int u = v - NV;
    const int e = u & 7, lane = (u >> 3) & 63, ks = (u >> 9) & 3,
              pf = (u >> 11) & 15, o = u >> 15;
    const int l = lane & 15, lh = lane >> 4;
    const int r = ks * 32 + lh * 8 + e, p = pf * 16 + l;
    utf[u] = (__bf16)U[((size_t)(o * RANK + r)) * 256 + p];
  }
}

// ---- K1: T-tile GEMM. wg=256 (4 waves), tile 64 rows x 128 r, one j. ----
// T stored j-major: T[j][n][128].
__global__ __launch_bounds__(256, 4) void k1_T(
    const float* __restrict__ x, const __bf16* __restrict__ vtf,
    __bf16* __restrict__ T)
{
  __shared__ __bf16 X_lds[64 * 256];   // 32 KB

  const int tid  = threadIdx.x;
  const int lane = tid & 63;
  const int w    = tid >> 6;
  const int l15  = lane & 15;
  const int lhi  = lane >> 4;
  const int mt   = blockIdx.x >> 4;
  const int j    = blockIdx.x & 15;
  const size_t rowbase = (size_t)mt * 64;

  #pragma unroll
  for (int i = 0; i < 16; ++i) {
    const int row = w * 16 + i;
    const f32x4 v = *(const f32x4*)(x + (rowbase + row) * IN_DIM + j * 256 + lane * 4);
    const int c = (lane >> 1) ^ (row & 15);
    *(bf16x4*)&X_lds[row * 256 + c * 8 + (lane & 1) * 4] = cvt4(v);
  }
  __syncthreads();

  f32x4 acc[2][4];
  #pragma unroll
  for (int a = 0; a < 2; ++a)
    #pragma unroll
    for (int b = 0; b < 4; ++b) acc[a][b] = (f32x4){0.f, 0.f, 0.f, 0.f};

  const __bf16* va = vtf + ((size_t)(j * 8 + w * 2) * 8) * 512 + lane * 8;
  #pragma unroll
  for (int ks = 0; ks < 8; ++ks) {
    bf16x8 bfr[4];
    #pragma unroll
    for (int nf = 0; nf < 4; ++nf) {
      const int c = (ks * 4 + lhi) ^ l15;
      bfr[nf] = *(const bf16x8*)&X_lds[(nf * 16 + l15) * 256 + c * 8];
    }
    const bf16x8 a0 = *(const bf16x8*)(va + (size_t)ks * 512);
    const bf16x8 a1 = *(const bf16x8*)(va + (size_t)(8 + ks) * 512);
    #pragma unroll
    for (int nf = 0; nf < 4; ++nf) {
      acc[0][nf] = __builtin_amdgcn_mfma_f32_16x16x32_bf16(a0, bfr[nf], acc[0][nf], 0, 0, 0);
      acc[1][nf] = __builtin_amdgcn_mfma_f32_16x16x32_bf16(a1, bfr[nf], acc[1][nf], 0, 0, 0);
    }
  }
  // store: D=[r,n]; T[j][rowbase + nf*16+l15][ (w*2+rfi)*16 + lhi*4 ..+4 ]
  #pragma unroll
  for (int rfi = 0; rfi < 2; ++rfi)
    #pragma unroll
    for (int nf = 0; nf < 4; ++nf) {
      *(bf16x4*)&T[((size_t)j * NROWS + rowbase + nf * 16 + l15) * RANK
                   + (w * 2 + rfi) * 16 + lhi * 4] = cvt4(acc[rfi][nf]);
    }
}

// ---- K2f: fused fold + out-GEMM. wg=256 (4 waves), 64 rows x one o. ----
// grid b: o = (b>>3)&15, mt = (b&7)*16 + (b>>7)  -> all 16 o's of an mt on one XCD.
__global__ __launch_bounds__(256, 4) void k2_fused(
    const __bf16* __restrict__ T, const float* __restrict__ S,
    const __bf16* __restrict__ utf, const float* __restrict__ bias,
    float* __restrict__ out)
{
  __shared__ float  S_lds[BJ * RANK];    // 8 KB, linear [j][r]
  __shared__ __bf16 u_lds[64 * RANK];    // 16 KB, 16B chunk c -> c ^ (n&15)

  const int tid = threadIdx.x;
  const int b   = blockIdx.x;
  const int o   = (b >> 3) & 15;
  const int mt  = (b & 7) * 16 + (b >> 7);
  const size_t rowbase = (size_t)mt * 64;

  // ---- stage S[o] linear, fully coalesced ----
  {
    const float* sb = S + (size_t)o * (BJ * RANK);
    #pragma unroll
    for (int h = 0; h < 2; ++h) {
      const int idx = tid + h * 256;                 // f32x4 index 0..511
      *(f32x4*)&S_lds[idx * 4] = *(const f32x4*)(sb + idx * 4);
    }
  }
  __syncthreads();

  // ---- fold in regs: thread = (n = tid>>2, rq = tid&3) ----
  // piece k covers r = k*32 + rq*8 .. +8 ; load addr byte = n*256 + rq*16 + k*64
  // -> per instruction: 16 segments x 64 B (full sectors).
  {
    const int n  = tid >> 2;
    const int rq = tid & 3;
    const __bf16* tg = T + (rowbase + n) * RANK + rq * 8;
    const size_t jstride = (size_t)NROWS * RANK;
    f32x4 uac[8];
    #pragma unroll
    for (int e = 0; e < 8; ++e) uac[e] = (f32x4){0.f, 0.f, 0.f, 0.f};

    #pragma unroll 4
    for (int jb = 0; jb < BJ; ++jb) {
      const __bf16* tj = tg + (size_t)jb * jstride;
      const bf16x8 tv0 = *(const bf16x8*)(tj);
      const bf16x8 tv1 = *(const bf16x8*)(tj + 32);
      const bf16x8 tv2 = *(const bf16x8*)(tj + 64);
      const bf16x8 tv3 = *(const bf16x8*)(tj + 96);
      const float* sj = &S_lds[jb * RANK + rq * 8];
      uac[0] = *(const f32x4*)(sj +  0) * lo4(tv0) + uac[0];
      uac[1] = *(const f32x4*)(sj +  4) * hi4(tv0) + uac[1];
      uac[2] = *(const f32x4*)(sj + 32) * lo4(tv1) + uac[2];
      uac[3] = *(const f32x4*)(sj + 36) * hi4(tv1) + uac[3];
      uac[4] = *(const f32x4*)(sj + 64) * lo4(tv2) + uac[4];
      uac[5] = *(const f32x4*)(sj + 68) * hi4(tv2) + uac[5];
      uac[6] = *(const f32x4*)(sj + 96) * lo4(tv3) + uac[6];
      uac[7] = *(const f32x4*)(sj + 100) * hi4(tv3) + uac[7];
    }
    // write u[n][r], chunk (k*4+rq) at swizzled slot
    #pragma unroll
    for (int k = 0; k < 4; ++k) {
      bf16x8 uw;
      const f32x4 a = uac[2 * k], bb = uac[2 * k + 1];
      uw[0] = (__bf16)a[0];  uw[1] = (__bf16)a[1];  uw[2] = (__bf16)a[2];  uw[3] = (__bf16)a[3];
      uw[4] = (__bf16)bb[0]; uw[5] = (__bf16)bb[1]; uw[6] = (__bf16)bb[2]; uw[7] = (__bf16)bb[3];
      const int swz = (k * 4 + rq) ^ (n & 15);
      *(bf16x8*)&u_lds[n * RANK + swz * 8] = uw;
    }
  }
  __syncthreads();

  // ---- out GEMM: wave w -> p = [w*64, +64); D=[p,n] -> f32x4 stores ----
  {
    const int lane = tid & 63;
    const int w    = tid >> 6;
    const int l15  = lane & 15;
    const int lhi  = lane >> 4;

    f32x4 acc[4][4];
    #pragma unroll
    for (int a = 0; a < 4; ++a)
      #pragma unroll
      for (int c = 0; c < 4; ++c) acc[a][c] = (f32x4){0.f, 0.f, 0.f, 0.f};

    #pragma unroll
    for (int ks = 0; ks < 4; ++ks) {
      bf16x8 ubf[4];
      #pragma unroll
      for (int nf = 0; nf < 4; ++nf) {
        const int swz = (ks * 4 + lhi) ^ l15;
        ubf[nf] = *(const bf16x8*)&u_lds[(nf * 16 + l15) * RANK + swz * 8];
      }
      #pragma unroll
      for (int pi = 0; pi < 4; ++pi) {
        const bf16x8 af = *(const bf16x8*)(
            utf + ((size_t)((o * 16 + w * 4 + pi) * 4 + ks)) * 512 + lane * 8);
        #pragma unroll
        for (int nf = 0; nf < 4; ++nf)
          acc[pi][nf] = __builtin_amdgcn_mfma_f32_16x16x32_bf16(af, ubf[nf], acc[pi][nf], 0, 0, 0);
      }
    }

    #pragma unroll
    for (int pi = 0; pi < 4; ++pi) {
      const int colb = o * 256 + (w * 4 + pi) * 16 + lhi * 4;
      const f32x4 bv = *(const f32x4*)(bias + colb);
      #pragma unroll
      for (int nf = 0; nf < 4; ++nf) {
        *(f32x4*)(out + (rowbase + nf * 16 + l15) * OUT_DIM + colb) = acc[pi][nf] + bv;
      }
    }
  }
}

extern "C" void kernel_launch(void* const* d_in, const int* in_sizes, int n_in,
                              void* d_out, int out_size, void* d_ws, size_t ws_size,
                              hipStream_t stream) {
  const float* x    = (const float*)d_in[0];
  const float* S    = (const float*)d_in[1];
  const float* U    = (const float*)d_in[2];
  const float* Vt   = (const float*)d_in[3];
  const float* bias = (const float*)d_in[4];
  float* out = (float*)d_out;

  __bf16* vtf = (__bf16*)d_ws;                       // 1 MB
  __bf16* utf = vtf + (size_t)BJ * 8 * 8 * 512;      // 1 MB
  __bf16* T   = utf + (size_t)BO * 16 * 4 * 512;     // 32 MB: T[16][8192][128]

  prep_frag<<<(2 * 524288) / 256, 256, 0, stream>>>(Vt, U, vtf, utf);
  k1_T<<<(NROWS / 64) * BJ, 256, 0, stream>>>(x, vtf, T);
  k2_fused<<<(NROWS / 64) * BO, 256, 0, stream>>>(T, S, utf, bias, out);
}